// Round 1
// baseline (399.319 us; speedup 1.0000x reference)
//
#include <hip/hip_runtime.h>

#define Bn   256      // batch
#define Dk   2048     // feature dim (K)
#define Cc   8        // cameras
#define Mm   2048     // proxies per camera
#define Nn   16384    // C*M
#define BG   50       // bg_knn
#define INV_T 20.0f   // 1/0.05
#define NEG_INF -3.0e38f

typedef __attribute__((ext_vector_type(8))) short bf16x8;
typedef __attribute__((ext_vector_type(4))) float f32x4;

__device__ inline short f2bf(float f) {
  unsigned u = __builtin_bit_cast(unsigned, f);
  u = (u + 0x7fffu + ((u >> 16) & 1u)) >> 16;   // RNE; inputs are finite
  return (short)u;
}

// ---------------------------------------------------------------- prep: zero loss, camera histogram
__global__ __launch_bounds__(256) void prep_kernel(const int* __restrict__ cams,
                                                   float* __restrict__ loss,
                                                   int* __restrict__ cnt) {
  int t = threadIdx.x;
  if (t < Cc) cnt[t] = 0;
  if (t == 0) loss[0] = 0.0f;
  __syncthreads();
  atomicAdd(&cnt[cams[t]], 1);
}

// ---------------------------------------------------------------- convert inputs f32 -> bf16
__global__ __launch_bounds__(256) void convert_kernel(const float* __restrict__ x,
                                                      short* __restrict__ a, int n4) {
  int i = blockIdx.x * 256 + threadIdx.x;
  if (i < n4) {
    float4 v = ((const float4*)x)[i];
    short4 h;
    h.x = f2bf(v.x); h.y = f2bf(v.y); h.z = f2bf(v.z); h.w = f2bf(v.w);
    ((short4*)a)[i] = h;
  }
}

// ---------------------------------------------------------------- GEMM sims = A @ em^T, fused em copy-out
// A: [256,2048] bf16.  em: [16384,2048] f32.  Tile: M=256 x N=64, BK=32. 512 threads (8 waves).
#define BK 32
#define BN 64
#define SA 40   // LDS row stride (bf16 elems): 32 + 8 pad
__global__ __launch_bounds__(512) void gemm_copy_kernel(const short* __restrict__ A,
                                                        const float* __restrict__ Em,
                                                        float* __restrict__ sims,
                                                        float* __restrict__ out_em) {
  __shared__ __align__(16) short As[Bn * SA];   // 20480 B
  __shared__ __align__(16) short Bs[BN * SA];   //  5120 B
  const int tid = threadIdx.x;
  const int nbase = blockIdx.x * BN;
  const int lane = tid & 63;
  const int w = tid >> 6;       // 0..7
  const int wm = w & 3;         // m-group of 64 rows
  const int wn = w >> 2;        // n-group of 32 cols
  const int lr = lane & 15;     // row within 16-subtile
  const int lq = lane >> 4;     // quad 0..3

  f32x4 acc[4][2];
#pragma unroll
  for (int mi = 0; mi < 4; ++mi)
#pragma unroll
    for (int ni = 0; ni < 2; ++ni) acc[mi][ni] = (f32x4)(0.0f);

  const int brow = tid >> 3, bseg = tid & 7;     // B staging: 64 rows x 8 float4
  for (int kt = 0; kt < Dk / BK; ++kt) {
    // ---- stage A tile (256 x 32 bf16): 1024 x 16B chunks, 2 per thread
#pragma unroll
    for (int c = 0; c < 2; ++c) {
      int l = tid + c * 512;
      int row = l >> 2, seg = l & 3;
      uint4 va = *(const uint4*)(A + (size_t)row * Dk + kt * BK + seg * 8);
      *(uint4*)(As + row * SA + seg * 8) = va;
    }
    // ---- stage B tile (64 x 32 f32 -> bf16) + copy-out f32
    {
      size_t go = (size_t)(nbase + brow) * Dk + kt * BK + bseg * 4;
      float4 vb = *(const float4*)(Em + go);
      short4 hb;
      hb.x = f2bf(vb.x); hb.y = f2bf(vb.y); hb.z = f2bf(vb.z); hb.w = f2bf(vb.w);
      *(short4*)(Bs + brow * SA + bseg * 4) = hb;
      out_em[go + 0] = vb.x; out_em[go + 1] = vb.y;   // out_em base is 4B-misaligned vs 16B: scalar stores
      out_em[go + 2] = vb.z; out_em[go + 3] = vb.w;
    }
    __syncthreads();
    // ---- MFMA: wave covers 64(m) x 32(n)
    bf16x8 af[4], bfr[2];
#pragma unroll
    for (int mi = 0; mi < 4; ++mi)
      af[mi] = *(const bf16x8*)(As + (wm * 64 + mi * 16 + lr) * SA + lq * 8);
#pragma unroll
    for (int ni = 0; ni < 2; ++ni)
      bfr[ni] = *(const bf16x8*)(Bs + (wn * 32 + ni * 16 + lr) * SA + lq * 8);
#pragma unroll
    for (int mi = 0; mi < 4; ++mi)
#pragma unroll
      for (int ni = 0; ni < 2; ++ni)
        acc[mi][ni] = __builtin_amdgcn_mfma_f32_16x16x32_bf16(af[mi], bfr[ni], acc[mi][ni], 0, 0, 0);
    __syncthreads();
  }
  // ---- epilogue: D[m][n], m = quad*4+reg, n = lane&15 within subtile
#pragma unroll
  for (int mi = 0; mi < 4; ++mi)
#pragma unroll
    for (int ni = 0; ni < 2; ++ni)
#pragma unroll
      for (int r = 0; r < 4; ++r) {
        int m = wm * 64 + mi * 16 + lq * 4 + r;
        int n = nbase + wn * 32 + ni * 16 + lr;
        sims[(size_t)m * Nn + n] = acc[mi][ni][r];
      }
}

// ---------------------------------------------------------------- loss: one wave per sample row
__global__ __launch_bounds__(64) void loss_kernel(const float* __restrict__ sims,
                                                  const int* __restrict__ targets,
                                                  const int* __restrict__ cams,
                                                  const int* __restrict__ cnt,
                                                  const int* __restrict__ epoch,
                                                  float* __restrict__ loss_out) {
  __shared__ __align__(16) float row[Nn];   // 64 KB
  const int b = blockIdx.x, tid = threadIdx.x;
  // load row (16384 f32) via float4
  {
    const float4* src = (const float4*)(sims + (size_t)b * Nn);
    float4* dst = (float4*)row;
    for (int i = tid; i < Nn / 4; i += 64) dst[i] = src[i];
  }
  __syncthreads();
  const int cam = cams[b], tgt = targets[b];
  const int cv = cnt[cam];
  const float invc = 1.0f / (float)(cv > 0 ? cv : 1);
  const int base = cam * Mm;
  // ---- intra-camera CE over the 2048-wide block
  float lm = NEG_INF;
  for (int i = tid; i < Mm; i += 64) lm = fmaxf(lm, row[base + i]);
#pragma unroll
  for (int off = 32; off; off >>= 1) lm = fmaxf(lm, __shfl_down(lm, off, 64));
  const float maxv = __shfl(lm, 0, 64);
  float ls = 0.0f;
  for (int i = tid; i < Mm; i += 64) ls += __expf((row[base + i] - maxv) * INV_T);
#pragma unroll
  for (int off = 32; off; off >>= 1) ls += __shfl_down(ls, off, 64);
  const float sumexp = __shfl(ls, 0, 64);
  float total = (__logf(sumexp) + (maxv - row[base + tgt]) * INV_T) * invc;

  if (*epoch >= 5) {
    // positives (read BEFORE masking), then mask them in LDS
    float pv[Cc];
#pragma unroll
    for (int c = 0; c < Cc; ++c) pv[c] = row[tgt + Mm * c];
    __syncthreads();
    if (tid < Cc) row[tgt + Mm * tid] = NEG_INF;
    __syncthreads();
    float mp = NEG_INF;
#pragma unroll
    for (int c = 0; c < Cc; ++c) mp = fmaxf(mp, pv[c]);
    // ---- tournament top-50: lane s owns segment [s*256, s*256+256)
    float cand_v; int cand_i;
    {
      float v = NEG_INF; int ii = 0;
      const float4* r4 = (const float4*)row;
      for (int j = 0; j < 64; ++j) {
        int i4 = tid * 64 + j;
        float4 x = r4[i4];
        if (x.x > v) { v = x.x; ii = i4 * 4 + 0; }
        if (x.y > v) { v = x.y; ii = i4 * 4 + 1; }
        if (x.z > v) { v = x.z; ii = i4 * 4 + 2; }
        if (x.w > v) { v = x.w; ii = i4 * 4 + 3; }
      }
      cand_v = v; cand_i = ii;
    }
    float cm = 0.0f, cs = 0.0f;
    for (int it = 0; it < BG; ++it) {
      float v = cand_v; int ii = cand_i; int owner = tid;
#pragma unroll
      for (int off = 32; off; off >>= 1) {
        float ov = __shfl_down(v, off, 64);
        int oi = __shfl_down(ii, off, 64);
        int oo = __shfl_down(owner, off, 64);
        if (ov > v) { v = ov; ii = oi; owner = oo; }
      }
      v = __shfl(v, 0, 64); ii = __shfl(ii, 0, 64); owner = __shfl(owner, 0, 64);
      if (it == 0) cm = fmaxf(mp, v);
      cs += __expf((v - cm) * INV_T);
      if (tid == 0) row[ii] = NEG_INF;
      __syncthreads();
      // cooperative rescan of segment `owner`: 64 float4, one per lane
      {
        int i4 = owner * 64 + tid;
        float4 x = ((const float4*)row)[i4];
        float nv = NEG_INF; int ni = 0;
        if (x.x > nv) { nv = x.x; ni = i4 * 4 + 0; }
        if (x.y > nv) { nv = x.y; ni = i4 * 4 + 1; }
        if (x.z > nv) { nv = x.z; ni = i4 * 4 + 2; }
        if (x.w > nv) { nv = x.w; ni = i4 * 4 + 3; }
#pragma unroll
        for (int off = 32; off; off >>= 1) {
          float ov = __shfl_down(nv, off, 64);
          int oi = __shfl_down(ni, off, 64);
          if (ov > nv) { nv = ov; ni = oi; }
        }
        nv = __shfl(nv, 0, 64); ni = __shfl(ni, 0, 64);
        if (tid == owner) { cand_v = nv; cand_i = ni; }
      }
      __syncthreads();
    }
#pragma unroll
    for (int c = 0; c < Cc; ++c) cs += __expf((pv[c] - cm) * INV_T);
    const float lse = cm * INV_T + __logf(cs);
    float al = 0.0f;
#pragma unroll
    for (int c = 0; c < Cc; ++c) al += pv[c] * INV_T - lse;
    al = -al * 0.125f;
    total += 0.5f * al * invc;
  }
  if (tid == 0) atomicAdd(loss_out, total);
}

// ---------------------------------------------------------------- EMA scatter update + renorm
// one block per sample; only the first block of each row processes that row's samples in order
__global__ __launch_bounds__(256) void ema_kernel(const float* __restrict__ em,
                                                  const float* __restrict__ inputs,
                                                  const int* __restrict__ targets,
                                                  const int* __restrict__ cams,
                                                  float* __restrict__ out_em) {
  const int b = blockIdx.x, tid = threadIdx.x;
  const int r = cams[b] * Mm + targets[b];
  for (int j = 0; j < b; ++j)
    if (cams[j] * Mm + targets[j] == r) return;   // not first occurrence (uniform branch)
  __shared__ float red[4];
  float v[8];
#pragma unroll
  for (int u = 0; u < 8; ++u) v[u] = em[(size_t)r * Dk + u * 256 + tid];
  const int lane = tid & 63, w = tid >> 6;
  for (int j = b; j < Bn; ++j) {
    if (cams[j] * Mm + targets[j] != r) continue;
#pragma unroll
    for (int u = 0; u < 8; ++u)
      v[u] = 0.2f * v[u] + 0.8f * inputs[(size_t)j * Dk + u * 256 + tid];
    float ss = 0.0f;
#pragma unroll
    for (int u = 0; u < 8; ++u) ss += v[u] * v[u];
#pragma unroll
    for (int off = 32; off; off >>= 1) ss += __shfl_down(ss, off, 64);
    if (lane == 0) red[w] = ss;
    __syncthreads();
    const float inv = 1.0f / sqrtf(red[0] + red[1] + red[2] + red[3]);
#pragma unroll
    for (int u = 0; u < 8; ++u) v[u] *= inv;
    __syncthreads();
  }
#pragma unroll
  for (int u = 0; u < 8; ++u) out_em[(size_t)r * Dk + u * 256 + tid] = v[u];
}

// ---------------------------------------------------------------- launch
extern "C" void kernel_launch(void* const* d_in, const int* in_sizes, int n_in,
                              void* d_out, int out_size, void* d_ws, size_t ws_size,
                              hipStream_t stream) {
  const float* inputs  = (const float*)d_in[0];
  const float* em      = (const float*)d_in[1];
  const int*   targets = (const int*)d_in[2];
  const int*   cams    = (const int*)d_in[3];
  const int*   epoch   = (const int*)d_in[4];
  float* loss   = (float*)d_out;
  float* out_em = (float*)d_out + 1;

  float* sims  = (float*)d_ws;                                        // 256*16384*4 = 16 MB
  short* a16   = (short*)((char*)d_ws + (size_t)Bn * Nn * 4);         // 1 MB
  int*   cnt   = (int*)((char*)d_ws + (size_t)Bn * Nn * 4 + (size_t)Bn * Dk * 2);

  hipLaunchKernelGGL(prep_kernel,    dim3(1),   dim3(256), 0, stream, cams, loss, cnt);
  hipLaunchKernelGGL(convert_kernel, dim3(512), dim3(256), 0, stream, inputs, a16, Bn * Dk / 4);
  hipLaunchKernelGGL(gemm_copy_kernel, dim3(Nn / BN), dim3(512), 0, stream, a16, em, sims, out_em);
  hipLaunchKernelGGL(loss_kernel,    dim3(Bn),  dim3(64),  0, stream, sims, targets, cams, cnt, epoch, loss);
  hipLaunchKernelGGL(ema_kernel,     dim3(Bn),  dim3(256), 0, stream, em, inputs, targets, cams, out_em);
}

// Round 4
// 374.603 us; speedup vs baseline: 1.0660x; 1.0660x over previous
//
#include <hip/hip_runtime.h>

#define Bn 256
#define Dk 2048
#define Cc 8
#define Mm 2048
#define Nn 16384
#define BG 50
#define INV_T 20.0f

typedef __attribute__((ext_vector_type(8))) short bf16x8;
typedef __attribute__((ext_vector_type(4))) float f32x4;

__device__ inline short f2bf(float f) {
  unsigned u = __builtin_bit_cast(unsigned, f);
  u = (u + 0x7fffu + ((u >> 16) & 1u)) >> 16;   // RNE, inputs finite
  return (short)u;
}
// order-isomorphic mapping float -> uint (monotone for all finite values)
__device__ inline unsigned f2ord(float f) {
  unsigned u = __builtin_bit_cast(unsigned, f);
  return (u & 0x80000000u) ? ~u : (u | 0x80000000u);
}
__device__ inline float ord2f(unsigned o) {
  unsigned u = (o & 0x80000000u) ? (o ^ 0x80000000u) : ~o;
  return __builtin_bit_cast(float, u);
}

// ---------------------------------------------------------------- prep: cam histogram, first-occurrence flags
__global__ __launch_bounds__(256) void prep_kernel(const int* __restrict__ cams,
                                                   const int* __restrict__ targets,
                                                   int* __restrict__ cnt,
                                                   int* __restrict__ rowArr,
                                                   int* __restrict__ first) {
  __shared__ int rs[Bn];
  __shared__ int lc[Cc];
  const int t = threadIdx.x;
  const int r = cams[t] * Mm + targets[t];
  rs[t] = r;
  if (t < Cc) lc[t] = 0;
  __syncthreads();
  atomicAdd(&lc[cams[t]], 1);
  __syncthreads();
  if (t < Cc) cnt[t] = lc[t];
  int fst = 1;
  for (int j = 0; j < t; ++j)
    if (rs[j] == r) fst = 0;
  rowArr[t] = r;
  first[t] = fst;
}

// ---------------------------------------------------------------- convert+pack A: f32 -> bf16, per-K-tile (BK=32) layout
// aPack[kt][row][k] : kt in [0,64), row in [0,256), k in [0,32)  => staging loads are lane-contiguous
__global__ __launch_bounds__(256) void convert_kernel(const float* __restrict__ x,
                                                      short* __restrict__ a, int n4) {
  int i = blockIdx.x * 256 + threadIdx.x;
  if (i >= n4) return;
  float4 v = ((const float4*)x)[i];
  int row = i >> 9, j = i & 511;          // 512 float4 per row
  int kt = j >> 3, off = (j & 7) * 4;     // 8 float4 per K-tile of 32
  short4 h;
  h.x = f2bf(v.x); h.y = f2bf(v.y); h.z = f2bf(v.z); h.w = f2bf(v.w);
  *(short4*)(a + (size_t)kt * (Bn * 32) + row * 32 + off) = h;
}

// ---------------------------------------------------------------- GEMM sims = A @ em^T, fused em copy-out
// BM=256, BN=64, BK=32, 512 threads (8 waves), grid 256, double-buffered LDS, 1 barrier/iter
#define SA 40   // LDS row stride in shorts (32 + 8 pad, keeps 16B alignment)
__global__ __launch_bounds__(512) void gemm_copy_kernel(const short* __restrict__ A,
                                                        const float* __restrict__ Em,
                                                        float* __restrict__ sims,
                                                        float* __restrict__ out_em) {
  __shared__ __align__(16) short As[2][Bn * SA];   // 2 x 20480 B
  __shared__ __align__(16) short Bs[2][64 * SA];   // 2 x  5120 B   (total 51200 B)
  const int tid = threadIdx.x;
  const int nbase = blockIdx.x * 64;
  const int lane = tid & 63;
  const int w = tid >> 6, wm = w & 3, wn = w >> 2;
  const int lr = lane & 15, lq = lane >> 4;

  f32x4 acc[4][2];
#pragma unroll
  for (int mi = 0; mi < 4; ++mi)
#pragma unroll
    for (int ni = 0; ni < 2; ++ni) acc[mi][ni] = (f32x4)(0.0f);

  // staging maps
  const int arow0 = tid >> 2, achk = (tid & 3) * 8;        // A: 1024 x 16B chunks, 2/thread
  const int brow = tid >> 3, bcol = (tid & 7) * 4;         // B: 64 rows x 32 f32, 4 f32/thread
  const size_t bgo_base = (size_t)(nbase + brow) * Dk + bcol;

  uint4 aReg0, aReg1;
  float4 bReg;
  // prologue: tile 0
  aReg0 = *(const uint4*)(A + tid * 8);
  aReg1 = *(const uint4*)(A + (tid + 512) * 8);
  bReg = *(const float4*)(Em + bgo_base);

  for (int kt = 0; kt < 64; ++kt) {
    short* as = As[kt & 1];
    short* bs = Bs[kt & 1];
    // ---- LDS write of current tile from regs
    *(uint4*)(as + arow0 * SA + achk) = aReg0;
    *(uint4*)(as + (arow0 + 128) * SA + achk) = aReg1;
    short4 hb;
    hb.x = f2bf(bReg.x); hb.y = f2bf(bReg.y); hb.z = f2bf(bReg.z); hb.w = f2bf(bReg.w);
    *(short4*)(bs + brow * SA + bcol) = hb;
    // ---- fused copy-out of em (base is 4B-misaligned vs 16B: dword stores)
    {
      size_t go = bgo_base + (size_t)kt * 32;
      out_em[go + 0] = bReg.x;
      out_em[go + 1] = bReg.y;
      out_em[go + 2] = bReg.z;
      out_em[go + 3] = bReg.w;
    }
    __syncthreads();
    // ---- prefetch next tile (in flight during compute)
    if (kt < 63) {
      const short* ap = A + (size_t)(kt + 1) * (Bn * 32);
      aReg0 = *(const uint4*)(ap + tid * 8);
      aReg1 = *(const uint4*)(ap + (tid + 512) * 8);
      bReg = *(const float4*)(Em + bgo_base + (size_t)(kt + 1) * 32);
    }
    // ---- compute on current buffer: wave covers 64(m) x 32(n)
    bf16x8 af[4], bfr[2];
#pragma unroll
    for (int mi = 0; mi < 4; ++mi)
      af[mi] = *(const bf16x8*)(as + (wm * 64 + mi * 16 + lr) * SA + lq * 8);
#pragma unroll
    for (int ni = 0; ni < 2; ++ni)
      bfr[ni] = *(const bf16x8*)(bs + (wn * 32 + ni * 16 + lr) * SA + lq * 8);
#pragma unroll
    for (int mi = 0; mi < 4; ++mi)
#pragma unroll
      for (int ni = 0; ni < 2; ++ni)
        acc[mi][ni] = __builtin_amdgcn_mfma_f32_16x16x32_bf16(af[mi], bfr[ni], acc[mi][ni], 0, 0, 0);
    // single barrier per iter is safe: the barrier at iter k+1 separates
    // compute(k) on buf k&1 from the ds_write at iter k+2 that reuses it
  }
  // ---- epilogue
#pragma unroll
  for (int mi = 0; mi < 4; ++mi)
#pragma unroll
    for (int ni = 0; ni < 2; ++ni)
#pragma unroll
      for (int r = 0; r < 4; ++r) {
        int m = wm * 64 + mi * 16 + lq * 4 + r;
        int n = nbase + wn * 32 + ni * 16 + lr;
        sims[(size_t)m * Nn + n] = acc[mi][ni][r];
      }
}

// ---------------------------------------------------------------- block reduction helpers (256 threads; LDS ptr non-volatile,
// ordering provided by __syncthreads; volatile generic ptrs hit a gfx950 backend bug)
__device__ inline float blockRedSumF(float v, float* red, int tid) {
#pragma unroll
  for (int off = 32; off; off >>= 1) v += __shfl_down(v, off, 64);
  if ((tid & 63) == 0) red[tid >> 6] = v;
  __syncthreads();
  float r = red[0] + red[1] + red[2] + red[3];
  __syncthreads();
  return r;
}
__device__ inline int blockRedSumI(int v, int* red, int tid) {
#pragma unroll
  for (int off = 32; off; off >>= 1) v += __shfl_down(v, off, 64);
  if ((tid & 63) == 0) red[tid >> 6] = v;
  __syncthreads();
  int r = red[0] + red[1] + red[2] + red[3];
  __syncthreads();
  return r;
}
__device__ inline float blockRedMaxF(float v, float* red, int tid) {
#pragma unroll
  for (int off = 32; off; off >>= 1) v = fmaxf(v, __shfl_down(v, off, 64));
  if ((tid & 63) == 0) red[tid >> 6] = v;
  __syncthreads();
  float r = fmaxf(fmaxf(red[0], red[1]), fmaxf(red[2], red[3]));
  __syncthreads();
  return r;
}
__device__ inline unsigned blockRedMaxU(unsigned v, unsigned* red, int tid) {
#pragma unroll
  for (int off = 32; off; off >>= 1) { unsigned o = __shfl_down(v, off, 64); v = o > v ? o : v; }
  if ((tid & 63) == 0) red[tid >> 6] = v;
  __syncthreads();
  unsigned r = red[0];
  r = red[1] > r ? red[1] : r; r = red[2] > r ? red[2] : r; r = red[3] > r ? red[3] : r;
  __syncthreads();
  return r;
}

// ---------------------------------------------------------------- loss: one block (256 thr) per sample row
// row held in registers (ordered-uint form); exact top-50 via 32-round bit bisection for v50
__global__ __launch_bounds__(256) void loss_kernel(const float* __restrict__ sims,
                                                   const int* __restrict__ targets,
                                                   const int* __restrict__ cams,
                                                   const int* __restrict__ cnt,
                                                   const int* __restrict__ epoch,
                                                   float* __restrict__ lossPartial) {
  __shared__ float redf[4];
  __shared__ int redi[4];
  __shared__ unsigned redu[4];
  __shared__ unsigned pordS[Cc];
  const int b = blockIdx.x, t = threadIdx.x;

  // load row: thread t holds elements (q*256+t)*4+s, q=0..15, s=0..3
  uint4 uarr[16];
  {
    const float4* src = (const float4*)(sims + (size_t)b * Nn);
#pragma unroll
    for (int q = 0; q < 16; ++q) {
      float4 v = src[q * 256 + t];
      uarr[q].x = f2ord(v.x); uarr[q].y = f2ord(v.y);
      uarr[q].z = f2ord(v.z); uarr[q].w = f2ord(v.w);
    }
  }
  const int cam = cams[b], tgt = targets[b];
  const int cg = cnt[cam];
  const float invc = 1.0f / (float)(cg > 0 ? cg : 1);

  // ---- positives p_c = tgt + 2048c: all owned by thread (tgt>>2)&255
  {
    const int owner = (tgt >> 2) & 255;
    if (t == owner) {
      const int slot = tgt & 3;
#pragma unroll
      for (int c = 0; c < Cc; ++c) {
        const int chunk = (tgt >> 10) + 2 * c;
        uint4 uc = uarr[0];
#pragma unroll
        for (int q = 1; q < 16; ++q)
          if (chunk == q) uc = uarr[q];
        unsigned po = uc.x;
        if (slot == 1) po = uc.y;
        else if (slot == 2) po = uc.z;
        else if (slot == 3) po = uc.w;
        pordS[c] = po;
      }
    }
  }
  __syncthreads();
  unsigned pord[Cc];
  float pv[Cc];
#pragma unroll
  for (int c = 0; c < Cc; ++c) { pord[c] = pordS[c]; pv[c] = ord2f(pord[c]); }

  // ---- intra-camera CE: camera block = chunks {2cam, 2cam+1} (8 values/thread)
  float cv[8];
  {
    uint4 u0 = uarr[0], u1 = uarr[1];
#pragma unroll
    for (int q = 0; q < 16; ++q) {
      if (2 * cam == q) u0 = uarr[q];
      if (2 * cam + 1 == q) u1 = uarr[q];
    }
    cv[0] = ord2f(u0.x); cv[1] = ord2f(u0.y); cv[2] = ord2f(u0.z); cv[3] = ord2f(u0.w);
    cv[4] = ord2f(u1.x); cv[5] = ord2f(u1.y); cv[6] = ord2f(u1.z); cv[7] = ord2f(u1.w);
  }
  float lm = cv[0];
#pragma unroll
  for (int k = 1; k < 8; ++k) lm = fmaxf(lm, cv[k]);
  const float maxv = blockRedMaxF(lm, redf, t);
  float ls = 0.0f;
#pragma unroll
  for (int k = 0; k < 8; ++k) ls += __expf((cv[k] - maxv) * INV_T);
  const float sumexp = blockRedSumF(ls, redf, t);
  float total = (__logf(sumexp) + (maxv - pv[cam]) * INV_T) * invc;

  if (*epoch >= 5) {
    // ---- exact 50th-largest of the masked multiset (positives excluded by count subtraction)
    unsigned cur = 0u;
#pragma unroll 1
    for (int bit = 31; bit >= 0; --bit) {
      const unsigned cand = cur | (1u << bit);
      int c = 0;
#pragma unroll
      for (int q = 0; q < 16; ++q)
        c += (uarr[q].x >= cand) + (uarr[q].y >= cand) + (uarr[q].z >= cand) + (uarr[q].w >= cand);
      int ctot = blockRedSumI(c, redi, t);
#pragma unroll
      for (int cc2 = 0; cc2 < Cc; ++cc2) ctot -= (pord[cc2] >= cand);
      if (ctot >= BG) cur = cand;
    }
    // strictly-greater count (for tie multiplicity at v50)
    int cg2 = 0;
#pragma unroll
    for (int q = 0; q < 16; ++q)
      cg2 += (uarr[q].x > cur) + (uarr[q].y > cur) + (uarr[q].z > cur) + (uarr[q].w > cur);
    int cgt = blockRedSumI(cg2, redi, t);
#pragma unroll
    for (int cc2 = 0; cc2 < Cc; ++cc2) cgt -= (pord[cc2] > cur);
    // stability shift m = row max (== max of cat candidates)
    unsigned um = 0u;
#pragma unroll
    for (int q = 0; q < 16; ++q) {
      um = uarr[q].x > um ? uarr[q].x : um;
      um = uarr[q].y > um ? uarr[q].y : um;
      um = uarr[q].z > um ? uarr[q].z : um;
      um = uarr[q].w > um ? uarr[q].w : um;
    }
    const unsigned umax = blockRedMaxU(um, redu, t);
    const float m = ord2f(umax);
    const float v50 = ord2f(cur);
    // sum of exp over top-50 masked + positives
    float s = 0.0f;
#pragma unroll
    for (int q = 0; q < 16; ++q) {
      if (uarr[q].x > cur) s += __expf((ord2f(uarr[q].x) - m) * INV_T);
      if (uarr[q].y > cur) s += __expf((ord2f(uarr[q].y) - m) * INV_T);
      if (uarr[q].z > cur) s += __expf((ord2f(uarr[q].z) - m) * INV_T);
      if (uarr[q].w > cur) s += __expf((ord2f(uarr[q].w) - m) * INV_T);
    }
    float S = blockRedSumF(s, redf, t);
    float psum = 0.0f;
#pragma unroll
    for (int cc2 = 0; cc2 < Cc; ++cc2) {
      if (pord[cc2] > cur) S -= __expf((pv[cc2] - m) * INV_T);   // remove positives from >v50 set
      S += __expf((pv[cc2] - m) * INV_T);                        // add all positives (cat)
      psum += pv[cc2];
    }
    S += (float)(BG - cgt) * __expf((v50 - m) * INV_T);          // ties at v50
    const float lse = m * INV_T + __logf(S);
    const float al = lse - psum * (INV_T / 8.0f);
    total += 0.5f * al * invc;
  }
  if (t == 0) lossPartial[b] = total;
}

// ---------------------------------------------------------------- finalize: sum 256 partials -> loss
__global__ __launch_bounds__(256) void finalize_kernel(const float* __restrict__ lossPartial,
                                                       float* __restrict__ loss) {
  __shared__ float redf[4];
  const int t = threadIdx.x;
  float v = lossPartial[t];
  const float r = blockRedSumF(v, redf, t);
  if (t == 0) loss[0] = r;
}

// ---------------------------------------------------------------- EMA scatter update + renorm
__global__ __launch_bounds__(256) void ema_kernel(const float* __restrict__ em,
                                                  const float* __restrict__ inputs,
                                                  const int* __restrict__ rowArr,
                                                  const int* __restrict__ first,
                                                  float* __restrict__ out_em) {
  const int b = blockIdx.x, tid = threadIdx.x;
  if (!first[b]) return;   // uniform per block
  const int r = rowArr[b];
  __shared__ int rows[Bn];
  __shared__ float red[4];
  rows[tid] = rowArr[tid];
  __syncthreads();
  float v[8];
#pragma unroll
  for (int u = 0; u < 8; ++u) v[u] = em[(size_t)r * Dk + u * 256 + tid];
  const int lane = tid & 63, w = tid >> 6;
  for (int j = b; j < Bn; ++j) {
    if (rows[j] != r) continue;   // uniform
#pragma unroll
    for (int u = 0; u < 8; ++u)
      v[u] = 0.2f * v[u] + 0.8f * inputs[(size_t)j * Dk + u * 256 + tid];
    float ss = 0.0f;
#pragma unroll
    for (int u = 0; u < 8; ++u) ss += v[u] * v[u];
#pragma unroll
    for (int off = 32; off; off >>= 1) ss += __shfl_down(ss, off, 64);
    if (lane == 0) red[w] = ss;
    __syncthreads();
    const float inv = 1.0f / sqrtf(red[0] + red[1] + red[2] + red[3]);
#pragma unroll
    for (int u = 0; u < 8; ++u) v[u] *= inv;
    __syncthreads();
  }
#pragma unroll
  for (int u = 0; u < 8; ++u) out_em[(size_t)r * Dk + u * 256 + tid] = v[u];
}

// ---------------------------------------------------------------- launch
extern "C" void kernel_launch(void* const* d_in, const int* in_sizes, int n_in,
                              void* d_out, int out_size, void* d_ws, size_t ws_size,
                              hipStream_t stream) {
  const float* inputs  = (const float*)d_in[0];
  const float* em      = (const float*)d_in[1];
  const int*   targets = (const int*)d_in[2];
  const int*   cams    = (const int*)d_in[3];
  const int*   epoch   = (const int*)d_in[4];
  float* loss   = (float*)d_out;
  float* out_em = (float*)d_out + 1;

  float* sims = (float*)d_ws;                                          // 16 MB
  short* a16  = (short*)((char*)d_ws + (size_t)Bn * Nn * 4);           // 1 MB packed A
  float* lossPartial = (float*)((char*)d_ws + (size_t)Bn * Nn * 4 + (size_t)Bn * Dk * 2);
  int* ibase  = (int*)(lossPartial + Bn);
  int* cnt    = ibase;
  int* rowArr = ibase + 8;
  int* first  = ibase + 8 + Bn;

  hipLaunchKernelGGL(prep_kernel,    dim3(1),       dim3(256), 0, stream, cams, targets, cnt, rowArr, first);
  hipLaunchKernelGGL(convert_kernel, dim3(512),     dim3(256), 0, stream, inputs, a16, Bn * Dk / 4);
  hipLaunchKernelGGL(gemm_copy_kernel, dim3(Nn / 64), dim3(512), 0, stream, a16, em, sims, out_em);
  hipLaunchKernelGGL(loss_kernel,    dim3(Bn),      dim3(256), 0, stream, sims, targets, cams, cnt, epoch, lossPartial);
  hipLaunchKernelGGL(finalize_kernel, dim3(1),      dim3(256), 0, stream, lossPartial, loss);
  hipLaunchKernelGGL(ema_kernel,     dim3(Bn),      dim3(256), 0, stream, em, inputs, rowArr, first, out_em);
}